// Round 9
// baseline (32894.476 us; speedup 1.0000x reference)
//
#include <hip/hip_runtime.h>
#include <stdint.h>

#define HH 256
#define BB 64
#define TT 1024
#define G4H 1024
#define NSL 16              // workgroups per direction (gate-split)
#define KC 16               // h-columns owned per WG
#define SPIN_LIM (1 << 16)  // per-wave retry budget (~16ms worst) -> fast wrong answer, no hang
#define TCHUNK 64           // t-steps per gx1_gemm block

typedef _Float16 v8h __attribute__((ext_vector_type(8)));
typedef float v4f __attribute__((ext_vector_type(4)));

union HFP8 { _Float16 h[8]; v8h v; };

__device__ __forceinline__ float fsig(float x) {
  float e = __builtin_amdgcn_exp2f(x * -1.44269504f);
  return __builtin_amdgcn_rcpf(1.f + e);
}
__device__ __forceinline__ float ftanh(float x) {
  float e = __builtin_amdgcn_exp2f(x * 2.88539008f);
  return 1.f - 2.f * __builtin_amdgcn_rcpf(e + 1.f);
}

// ---------------- prep kernels ----------------
__global__ void prep_w1(const float* __restrict__ w, _Float16* __restrict__ wh) {
  int i = blockIdx.x * 256 + threadIdx.x;
  if (i < 2 * 1024 * 512) wh[i] = (_Float16)w[i];
}

// xpad[d][t][b][32] fp16 : x (or reversed x) padded to K=32
__global__ void prep_x(const float* __restrict__ x, const int* __restrict__ lengths,
                       _Float16* __restrict__ xpad) {
  int i = blockIdx.x * 256 + threadIdx.x;
  if (i >= 2 * TT * BB * 32) return;
  int k = i & 31, bb = (i >> 5) & 63, t = (i >> 11) & 1023, d = (i >> 21) & 1;
  float v = 0.f;
  if (k < 3) {
    int L = lengths[bb];
    int rt = (d == 0) ? t : ((t < L) ? (L - 1 - t) : t);
    v = x[((size_t)bb * TT + rt) * 3 + k];
  }
  xpad[i] = (_Float16)v;
}

// ---------------- layer-1 gate-init GEMM (hoisted, PHASED, fp32 out) ----------------
// h1 layout [t][d][b][256] in SCAN-STEP order (bwd not re-reversed). Input row of
// layer-1 dir d at scan step t = [h1[p][0][b], h1[s][1][b]] with
// p = (d==0)? t : ((t<L)? L-1-t : t),  s = (p<L)? L-1-p : p   (for d==1, s==t).
// Output gxq[tloc][d][gate][b] fp32 for t in [t0, t0 + 64*gridT).
__global__ __launch_bounds__(256, 1)
void gx1_gemm(const _Float16* __restrict__ h1, const _Float16* __restrict__ w1h,
              const int* __restrict__ lengths, float* __restrict__ gxq, int t0) {
  const int blk = blockIdx.x;
  const int d = blk & 1;
  const int g = (blk >> 1) & 15;
  const int tc = blk >> 5;
  const int tid = threadIdx.x;
  const int w = tid >> 6;
  const int l = tid & 63;
  const int l15 = l & 15;
  const int hp = l >> 4;
  const int col = g * KC + l15;

  // B-fragments: W_ih_l1 rows {nt*256+col}, K=512 (k<256 fwd half, k>=256 bwd half)
  v8h wf[16][4];
#pragma unroll
  for (int kt = 0; kt < 16; ++kt)
#pragma unroll
    for (int nt = 0; nt < 4; ++nt)
      wf[kt][nt] =
          *(const v8h*)(w1h + ((size_t)d * G4H + nt * HH + col) * 512 + kt * 32 + hp * 8);

  const int b = w * 16 + l15;  // this lane's A-row (batch)
  const int L = lengths[b];

  for (int i = 0; i < TCHUNK; ++i) {
    const int t = t0 + tc * TCHUNK + i;
    const int tloc = t - t0;
    const int p = (d == 0) ? t : ((t < L) ? (L - 1 - t) : t);
    const int s = (p < L) ? (L - 1 - p) : p;
    const _Float16* afwd = h1 + (((size_t)p * 2 + 0) * BB + b) * HH + hp * 8;
    const _Float16* abwd = h1 + (((size_t)s * 2 + 1) * BB + b) * HH + hp * 8;
    v4f acc[4];
#pragma unroll
    for (int nt = 0; nt < 4; ++nt) acc[nt] = v4f{0.f, 0.f, 0.f, 0.f};
#pragma unroll
    for (int kt = 0; kt < 8; ++kt) {
      const v8h a = *(const v8h*)(afwd + kt * 32);
#pragma unroll
      for (int nt = 0; nt < 4; ++nt)
        acc[nt] = __builtin_amdgcn_mfma_f32_16x16x32_f16(a, wf[kt][nt], acc[nt], 0, 0, 0);
    }
#pragma unroll
    for (int kt = 8; kt < 16; ++kt) {
      const v8h a = *(const v8h*)(abwd + (kt - 8) * 32);
#pragma unroll
      for (int nt = 0; nt < 4; ++nt)
        acc[nt] = __builtin_amdgcn_mfma_f32_16x16x32_f16(a, wf[kt][nt], acc[nt], 0, 0, 0);
    }
    // C-frag: row(b') = w*16+hp*4+r, col(gate) = nt*256+col -> one 16B store per nt
    float* drow = gxq + (((size_t)tloc * 2 + d) * G4H) * (size_t)BB + w * 16 + hp * 4;
#pragma unroll
    for (int nt = 0; nt < 4; ++nt)
      *(v4f*)(drow + (size_t)(nt * HH + col) * BB) = acc[nt];
  }
}

// ---------------- persistent gate-split LSTM scan (TAGGED exchange, 1-RT) ----------------
// grid 128; active blocks: (blk&7)<2 -> dir d = blk&7, slice g = blk>>3 (0..15).
// Exchange word = (tag16<<16)|h_fp16 in u32 hexu[d][parity][b][col]. Writer: 4 relaxed
// agent u32 stores per lane, NO vmcnt, NO separate publish — the tag travels with the
// data (4B word atomicity). Reader (per-wave plane w): load its 64 words, accept only
// if EVERY tag == TAGBASE+t-1, else s_sleep+retry. One visibility leg per step.
// Safety: plane-closed double buffer — a writer reaches t+2 (overwriting parity t&1)
// only after reading tag t+1 from ALL 16 plane WGs; that tag-(t+1) store is
// data-dependent on the peer's completed tag-t reads, so no overwrite-before-read.
// Exact-match tags + TAGBASE=1024*layer (disambiguates layer-0 residue) + h_ex
// pre-memset 0xFF (tag 0xFFFF never expected) kill ABA. Memset is captured inside
// kernel_launch -> re-runs on every graph replay.
// Watchdog: per-wave retry budget, wave-uniform break, no barriers -> no hang.
// GX==1: gate-init from fp32 gxq, register-prefetched one step ahead, added AFTER the
// recurrent MFMAs (load latency hides under poll+MFMA). GX==0: in-scan GEMM fallback.
// Phasing (LAYER 1): [t0,t1) window; c/h carried via cst across launches.
template <int LAYER, int GX>
__global__ __launch_bounds__(256, 1)
void lstm_scan(const float* __restrict__ Whh, const float* __restrict__ Wih0,
               const float* __restrict__ bih, const float* __restrict__ bhh,
               const _Float16* __restrict__ xpad, const float* __restrict__ gxq,
               const _Float16* __restrict__ h1in,
               _Float16* __restrict__ h1out, float* __restrict__ feat,
               unsigned* __restrict__ h_ex,
               const int* __restrict__ lengths, float* __restrict__ cst,
               int t0, int t1) {
  const int blk = blockIdx.x;
  if ((blk & 7) >= 2) return;
  const int d = blk & 7;
  const int g = blk >> 3;
  const int tid = threadIdx.x;
  const int w = tid >> 6;        // wave id = batch tile = sync plane
  const int l = tid & 63;
  const int l15 = l & 15;
  const int hp = l >> 4;
  const int col = g * KC + l15;  // owned h-column
  const unsigned TAGBASE = LAYER * 1024u;

  // persistent W_hh fragments (B-operand layout: lane = W[j=nt*256+col][k=kt*32+hp*8+e])
  v8h wfrag[8][4];
#pragma unroll
  for (int kt = 0; kt < 8; ++kt) {
#pragma unroll
    for (int nt = 0; nt < 4; ++nt) {
      const int j = nt * HH + col;
      const float* src = Whh + ((size_t)d * G4H + j) * HH + kt * 32 + hp * 8;
      HFP8 p;
#pragma unroll
      for (int e = 0; e < 8; ++e) p.h[e] = (_Float16)src[e];
      wfrag[kt][nt] = p.v;
    }
  }
  float bias[4];
#pragma unroll
  for (int nt = 0; nt < 4; ++nt)
    bias[nt] = bih[d * G4H + nt * HH + col] + bhh[d * G4H + nt * HH + col];

  v8h xfrag[4];  // layer 0: W_ih_l0 (K=3 padded to 32)
  if (LAYER == 0) {
#pragma unroll
    for (int nt = 0; nt < 4; ++nt) {
      const int j = nt * HH + col;
      HFP8 p;
#pragma unroll
      for (int e = 0; e < 8; ++e) {
        const int kl = hp * 8 + e;
        p.h[e] = (kl < 3) ? (_Float16)Wih0[((size_t)d * G4H + j) * 3 + kl] : (_Float16)0.f;
      }
      xfrag[nt] = p.v;
    }
  }
  v8h w1frag[16][4];  // layer-1 fallback: W_ih_l1 slice, B-fragments (K=512)
  if (LAYER == 1 && GX == 0) {
#pragma unroll
    for (int kt = 0; kt < 16; ++kt)
#pragma unroll
      for (int nt = 0; nt < 4; ++nt)
        w1frag[kt][nt] =
            *(const v8h*)((const _Float16*)Wih0 +  // reuse Wih0 slot for w1h
                          ((size_t)d * G4H + nt * HH + col) * 512 + kt * 32 + hp * 8);
  }

  int Lr[4];
#pragma unroll
  for (int r = 0; r < 4; ++r) Lr[r] = lengths[w * 16 + hp * 4 + r];
  const int bb = w * 16 + l15;
  const int La = lengths[bb];  // lane's A-row length (fallback path)

  float c_reg[4] = {0.f, 0.f, 0.f, 0.f};
  float h_reg[4] = {0.f, 0.f, 0.f, 0.f};
  if (LAYER == 1 && t0 > 0) {  // phased restore (written by previous launch)
#pragma unroll
    for (int r = 0; r < 4; ++r) {
      const size_t ix = ((size_t)d * BB + (w * 16 + hp * 4 + r)) * HH + col;
      c_reg[r] = cst[ix];
      h_reg[r] = cst[(size_t)2 * BB * HH + ix];
    }
  }

  unsigned* hexu_d = h_ex + (size_t)d * 2 * BB * HH;  // u32 words, parity-double-buffered
  int guard = 0;

  // prefetch gate-init input for first step
  v8h xr;      // layer 0
  v4f gxr[4];  // layer 1 (GX path, fp32)
  if (LAYER == 0) {
    xr = *(const v8h*)(xpad + (((size_t)d * TT + t0) * BB + bb) * 32 + hp * 8);
  } else if (GX) {
    const float* gp = gxq + ((size_t)0 * 2 + d) * G4H * (size_t)BB + w * 16 + hp * 4;
#pragma unroll
    for (int nt = 0; nt < 4; ++nt)
      gxr[nt] = *(const v4f*)(gp + (size_t)(nt * HH + col) * BB);
  }

  for (int t = t0; t < t1; ++t) {
    v4f acc[4];
#pragma unroll
    for (int nt = 0; nt < 4; ++nt) acc[nt] = v4f{bias[nt], bias[nt], bias[nt], bias[nt]};

    if (LAYER == 1 && GX == 0) {
      // fallback in-scan gate GEMM (memory-fed; BEFORE the poll to overlap)
      const int p = (d == 0) ? t : ((t < La) ? (La - 1 - t) : t);
      const int s = (p < La) ? (La - 1 - p) : p;
      const _Float16* afwd = h1in + (((size_t)p * 2 + 0) * BB + bb) * HH + hp * 8;
      const _Float16* abwd = h1in + (((size_t)s * 2 + 1) * BB + bb) * HH + hp * 8;
#pragma unroll
      for (int kt = 0; kt < 8; ++kt) {
        const v8h a = *(const v8h*)(afwd + kt * 32);
#pragma unroll
        for (int nt = 0; nt < 4; ++nt)
          acc[nt] = __builtin_amdgcn_mfma_f32_16x16x32_f16(a, w1frag[kt][nt], acc[nt], 0, 0, 0);
      }
#pragma unroll
      for (int kt = 8; kt < 16; ++kt) {
        const v8h a = *(const v8h*)(abwd + (kt - 8) * 32);
#pragma unroll
        for (int nt = 0; nt < 4; ++nt)
          acc[nt] = __builtin_amdgcn_mfma_f32_16x16x32_f16(a, w1frag[kt][nt], acc[nt], 0, 0, 0);
      }
    }

    if (t > 0) {
      // tagged exchange read: 64 u32 words (this lane's A-row slice), retry till all
      // tags match. The successful attempt IS the data read — single visibility leg.
      const unsigned* srcu = hexu_d + ((t - 1) & 1) * BB * HH;
      const int rowbase = bb * HH + hp * 8;
      const unsigned expw = TAGBASE + (unsigned)(t - 1);
      unsigned fw[64];
      int ok = 1;
      for (;;) {
        int good = 1;
#pragma unroll
        for (int kt = 0; kt < 8; ++kt)
#pragma unroll
          for (int e = 0; e < 8; ++e)
            fw[kt * 8 + e] = __hip_atomic_load(&srcu[rowbase + kt * 32 + e],
                                               __ATOMIC_RELAXED, __HIP_MEMORY_SCOPE_AGENT);
#pragma unroll
        for (int i = 0; i < 64; ++i) good &= ((fw[i] >> 16) == expw);
        if (__all(good)) break;
        __builtin_amdgcn_s_sleep(1);
        if (++guard > SPIN_LIM) { ok = 0; break; }
      }
      if (!ok) break;  // wave-uniform; starved peers also time out. No hang.

      // pack fp16 low-halves -> A-fragments, MFMA
#pragma unroll
      for (int kt = 0; kt < 8; ++kt) {
        union { unsigned u[4]; v8h v; } pk;
#pragma unroll
        for (int pr = 0; pr < 4; ++pr)
          pk.u[pr] = (fw[kt * 8 + 2 * pr] & 0xffffu) | (fw[kt * 8 + 2 * pr + 1] << 16);
#pragma unroll
        for (int nt = 0; nt < 4; ++nt)
          acc[nt] = __builtin_amdgcn_mfma_f32_16x16x32_f16(pk.v, wfrag[kt][nt], acc[nt], 0, 0, 0);
      }
    }

    // gate-init contribution AFTER the recurrent MFMAs (prefetch latency hidden)
    if (LAYER == 0) {
#pragma unroll
      for (int nt = 0; nt < 4; ++nt)
        acc[nt] = __builtin_amdgcn_mfma_f32_16x16x32_f16(xr, xfrag[nt], acc[nt], 0, 0, 0);
    } else if (GX) {
#pragma unroll
      for (int nt = 0; nt < 4; ++nt) acc[nt] += gxr[nt];
    }

    unsigned* dstu = hexu_d + (t & 1) * BB * HH;
    const unsigned tagw = (TAGBASE + (unsigned)t) << 16;
#pragma unroll
    for (int r = 0; r < 4; ++r) {
      const int m = w * 16 + hp * 4 + r;
      const float iv = acc[0][r], fv = acc[1][r], gv = acc[2][r], ov = acc[3][r];
      const float cn = fsig(fv) * c_reg[r] + fsig(iv) * ftanh(gv);
      const float hn = fsig(ov) * ftanh(cn);
      const bool valid = t < Lr[r];
      if (valid) { c_reg[r] = cn; h_reg[r] = hn; }
      union { _Float16 f; unsigned short s; } hb;
      hb.f = (_Float16)h_reg[r];
      __hip_atomic_store(&dstu[m * HH + col], tagw | (unsigned)hb.s, __ATOMIC_RELAXED,
                         __HIP_MEMORY_SCOPE_AGENT);
      if (LAYER == 1 && d == 1 && t == 0) {
        feat[m * 512 + HH + col] = h_reg[r];  // bwd out at orig t=L-1 == first bwd step
      }
    }
    // NO vmcnt, NO publish: the tagged stores drain on their own; readers retry.

    // ---- off the critical path ----
    if (LAYER == 0) {  // h1 store, coalesced [t][d][b][256], scan-step order
      _Float16* hr = h1out + (((size_t)t * 2 + d) * BB) * HH + col;
#pragma unroll
      for (int r = 0; r < 4; ++r)
        hr[(size_t)(w * 16 + hp * 4 + r) * HH] =
            (t < Lr[r]) ? (_Float16)h_reg[r] : (_Float16)0.f;
    }
    // next-step gate-init prefetch (flies during the next poll window)
    const int tp = (t + 1 < t1) ? t + 1 : t;
    if (LAYER == 0) {
      xr = *(const v8h*)(xpad + (((size_t)d * TT + tp) * BB + bb) * 32 + hp * 8);
    } else if (GX) {
      const float* gp =
          gxq + (((size_t)(tp - t0) * 2 + d) * G4H) * (size_t)BB + w * 16 + hp * 4;
#pragma unroll
      for (int nt = 0; nt < 4; ++nt)
        gxr[nt] = *(const v4f*)(gp + (size_t)(nt * HH + col) * BB);
    }
  }

  if (LAYER == 1 && t1 < TT) {  // phased save
#pragma unroll
    for (int r = 0; r < 4; ++r) {
      const size_t ix = ((size_t)d * BB + (w * 16 + hp * 4 + r)) * HH + col;
      cst[ix] = c_reg[r];
      cst[(size_t)2 * BB * HH + ix] = h_reg[r];
    }
  }
  if (LAYER == 1 && d == 0 && t1 == TT) {  // fwd final state (frozen at t=L-1)
#pragma unroll
    for (int r = 0; r < 4; ++r) feat[(w * 16 + hp * 4 + r) * 512 + col] = h_reg[r];
  }
}

// ---------------- head ----------------
__global__ void head_fc1(const float* __restrict__ feat, const float* __restrict__ w,
                         const float* __restrict__ b, float* __restrict__ y) {
  const int bb = blockIdx.x, o = threadIdx.x;
  __shared__ float f[512];
  f[o] = feat[bb * 512 + o];
  f[o + 256] = feat[bb * 512 + 256 + o];
  __syncthreads();
  float acc = b[o];
  const float* wr = w + (size_t)o * 512;
  for (int i = 0; i < 512; ++i) acc = fmaf(f[i], wr[i], acc);
  y[bb * 256 + o] = fmaxf(acc, 0.f);
}
__global__ void head_bn(const float* __restrict__ y, const float* __restrict__ gamma,
                        const float* __restrict__ beta, float* __restrict__ ss) {
  const int o = threadIdx.x;
  float s1 = 0.f, s2 = 0.f;
  for (int b = 0; b < 64; ++b) { const float v = y[b * 256 + o]; s1 += v; s2 += v * v; }
  const float mean = s1 * 0.015625f;
  const float var = s2 * 0.015625f - mean * mean;
  const float sc = gamma[o] * __builtin_amdgcn_rsqf(var + 1e-5f);
  ss[o] = sc;
  ss[256 + o] = beta[o] - mean * sc;
}
__global__ void head_out(const float* __restrict__ y, const float* __restrict__ ss,
                         const float* __restrict__ w, const float* __restrict__ b,
                         float* __restrict__ out) {
  const int bb = blockIdx.x, q = threadIdx.x;
  __shared__ float z[256];
  z[q] = y[bb * 256 + q] * ss[q] + ss[256 + q];
  __syncthreads();
  if (q < 196) {
    float acc = b[q];
    const float* wr = w + (size_t)q * 256;
    for (int o = 0; o < 256; ++o) acc = fmaf(z[o], wr[o], acc);
    out[bb * 196 + q] = acc;
  }
}

extern "C" void kernel_launch(void* const* d_in, const int* in_sizes, int n_in,
                              void* d_out, int out_size, void* d_ws, size_t ws_size,
                              hipStream_t stream) {
  const float* x       = (const float*)d_in[0];
  const int* lengths   = (const int*)d_in[1];
  const float* W_ih_l0 = (const float*)d_in[2];
  const float* W_hh_l0 = (const float*)d_in[3];
  const float* b_ih_l0 = (const float*)d_in[4];
  const float* b_hh_l0 = (const float*)d_in[5];
  const float* W_ih_l1 = (const float*)d_in[6];
  const float* W_hh_l1 = (const float*)d_in[7];
  const float* b_ih_l1 = (const float*)d_in[8];
  const float* b_hh_l1 = (const float*)d_in[9];
  const float* fc1_w   = (const float*)d_in[10];
  const float* fc1_b   = (const float*)d_in[11];
  const float* bn_g    = (const float*)d_in[12];
  const float* bn_b    = (const float*)d_in[13];
  const float* fco_w   = (const float*)d_in[14];
  const float* fco_b   = (const float*)d_in[15];
  float* out = (float*)d_out;

  char* ws = (char*)d_ws;
  size_t off = 0;
  auto alloc = [&](size_t sz) { char* p = ws + off; off += (sz + 255) & ~(size_t)255; return p; };
  float* feat      = (float*)alloc(BB * 512 * 4);
  float* ybuf      = (float*)alloc(BB * 256 * 4);
  float* ss        = (float*)alloc(2 * 256 * 4);
  unsigned* h_ex   = (unsigned*)alloc((size_t)2 * 2 * BB * HH * 4);   // tagged u32 words
  float* cst       = (float*)alloc(2 * 2 * BB * HH * 4);              // c|h phase carry
  _Float16* w1h    = (_Float16*)alloc((size_t)2 * 1024 * 512 * 2);
  _Float16* h1     = (_Float16*)alloc((size_t)TT * 2 * BB * HH * 2);  // [t][d][b][256]
  size_t xpad_off  = off;
  _Float16* xpad   = (_Float16*)alloc((size_t)2 * TT * BB * 32 * 2);
  // base total ~78 MB

  if (off > ws_size) {  // distinct signal: NaN output instead of zeros
    hipMemsetAsync(d_out, 0xFF, (size_t)out_size * 4, stream);
    return;
  }

  // gx buffer (fp32) overlays xpad (dead after scan0) and all tail space.
  // CH = t-steps per phase that fit; < TCHUNK -> in-scan fallback.
  const size_t perT = (size_t)2 * G4H * BB * 4;  // 512 KB per t-step (both dirs)
  size_t gx_avail = ws_size - xpad_off;
  int CH = (int)(gx_avail / perT);
  if (CH > TT) CH = TT;
  CH &= ~(TCHUNK - 1);
  float* gxbuf = (float*)(ws + xpad_off);

  // h_ex -> 0xFF: tag 0xFFFF never matches any expected tag (<= 2047)
  hipMemsetAsync(h_ex, 0xFF, (size_t)2 * 2 * BB * HH * 4, stream);

  prep_w1<<<(2 * 1024 * 512 + 255) / 256, 256, 0, stream>>>(W_ih_l1, w1h);
  prep_x<<<(2 * TT * BB * 32 + 255) / 256, 256, 0, stream>>>(x, lengths, xpad);

  lstm_scan<0, 0><<<128, 256, 0, stream>>>(W_hh_l0, W_ih_l0, b_ih_l0, b_hh_l0, xpad,
                                           nullptr, nullptr, h1, nullptr, h_ex,
                                           lengths, nullptr, 0, TT);
  if (CH >= TCHUNK) {
    const int np = (TT + CH - 1) / CH;
    for (int k = 0; k < np; ++k) {
      const int t0 = k * CH;
      const int t1 = (t0 + CH < TT) ? (t0 + CH) : TT;
      gx1_gemm<<<2 * 16 * ((t1 - t0) / TCHUNK), 256, 0, stream>>>(h1, w1h, lengths,
                                                                  gxbuf, t0);
      lstm_scan<1, 1><<<128, 256, 0, stream>>>(W_hh_l1, nullptr, b_ih_l1, b_hh_l1,
                                               nullptr, gxbuf, h1, nullptr, feat, h_ex,
                                               lengths, cst, t0, t1);
    }
  } else {  // fallback: in-scan gate GEMM (w1h passed through the Wih0 slot)
    lstm_scan<1, 0><<<128, 256, 0, stream>>>(W_hh_l1, (const float*)w1h, b_ih_l1,
                                             b_hh_l1, nullptr, nullptr, h1, nullptr,
                                             feat, h_ex, lengths, cst, 0, TT);
  }

  head_fc1<<<64, 256, 0, stream>>>(feat, fc1_w, fc1_b, ybuf);
  head_bn<<<1, 256, 0, stream>>>(ybuf, bn_g, bn_b, ss);
  head_out<<<64, 256, 0, stream>>>(ybuf, ss, fco_w, fco_b, out);
}

// Round 10
// 9390.932 us; speedup vs baseline: 3.5028x; 3.5028x over previous
//
#include <hip/hip_runtime.h>
#include <stdint.h>

#define HH 256
#define BB 64
#define TT 1024
#define G4H 1024
#define NSL 16              // workgroups per direction (gate-split)
#define KC 16               // h-columns owned per WG
#define SPIN_LIM (1 << 17)  // per-wave cumulative A+B retry budget -> fast wrong answer, no hang
#define TCHUNK 64           // t-steps per gx1_gemm block

typedef _Float16 v8h __attribute__((ext_vector_type(8)));
typedef float v4f __attribute__((ext_vector_type(4)));
typedef unsigned u32x4 __attribute__((ext_vector_type(4)));

union HFP8 { _Float16 h[8]; v8h v; };

__device__ __forceinline__ float fsig(float x) {
  float e = __builtin_amdgcn_exp2f(x * -1.44269504f);
  return __builtin_amdgcn_rcpf(1.f + e);
}
__device__ __forceinline__ float ftanh(float x) {
  float e = __builtin_amdgcn_exp2f(x * 2.88539008f);
  return 1.f - 2.f * __builtin_amdgcn_rcpf(e + 1.f);
}

// ---------------- prep kernels ----------------
__global__ void prep_w1(const float* __restrict__ w, _Float16* __restrict__ wh) {
  int i = blockIdx.x * 256 + threadIdx.x;
  if (i < 2 * 1024 * 512) wh[i] = (_Float16)w[i];
}

// xpad[d][t][b][32] fp16 : x (or reversed x) padded to K=32
__global__ void prep_x(const float* __restrict__ x, const int* __restrict__ lengths,
                       _Float16* __restrict__ xpad) {
  int i = blockIdx.x * 256 + threadIdx.x;
  if (i >= 2 * TT * BB * 32) return;
  int k = i & 31, bb = (i >> 5) & 63, t = (i >> 11) & 1023, d = (i >> 21) & 1;
  float v = 0.f;
  if (k < 3) {
    int L = lengths[bb];
    int rt = (d == 0) ? t : ((t < L) ? (L - 1 - t) : t);
    v = x[((size_t)bb * TT + rt) * 3 + k];
  }
  xpad[i] = (_Float16)v;
}

// ---------------- layer-1 gate-init GEMM (hoisted, PHASED, fp32 out) ----------------
// h1 layout [t][d][b][256] in SCAN-STEP order (bwd not re-reversed). Input row of
// layer-1 dir d at scan step t = [h1[p][0][b], h1[s][1][b]] with
// p = (d==0)? t : ((t<L)? L-1-t : t),  s = (p<L)? L-1-p : p   (for d==1, s==t).
// Output gxq[tloc][d][gate][b] fp32 for t in [t0, t0 + 64*gridT).
__global__ __launch_bounds__(256, 1)
void gx1_gemm(const _Float16* __restrict__ h1, const _Float16* __restrict__ w1h,
              const int* __restrict__ lengths, float* __restrict__ gxq, int t0) {
  const int blk = blockIdx.x;
  const int d = blk & 1;
  const int g = (blk >> 1) & 15;
  const int tc = blk >> 5;
  const int tid = threadIdx.x;
  const int w = tid >> 6;
  const int l = tid & 63;
  const int l15 = l & 15;
  const int hp = l >> 4;
  const int col = g * KC + l15;

  // B-fragments: W_ih_l1 rows {nt*256+col}, K=512 (k<256 fwd half, k>=256 bwd half)
  v8h wf[16][4];
#pragma unroll
  for (int kt = 0; kt < 16; ++kt)
#pragma unroll
    for (int nt = 0; nt < 4; ++nt)
      wf[kt][nt] =
          *(const v8h*)(w1h + ((size_t)d * G4H + nt * HH + col) * 512 + kt * 32 + hp * 8);

  const int b = w * 16 + l15;  // this lane's A-row (batch)
  const int L = lengths[b];

  for (int i = 0; i < TCHUNK; ++i) {
    const int t = t0 + tc * TCHUNK + i;
    const int tloc = t - t0;
    const int p = (d == 0) ? t : ((t < L) ? (L - 1 - t) : t);
    const int s = (p < L) ? (L - 1 - p) : p;
    const _Float16* afwd = h1 + (((size_t)p * 2 + 0) * BB + b) * HH + hp * 8;
    const _Float16* abwd = h1 + (((size_t)s * 2 + 1) * BB + b) * HH + hp * 8;
    v4f acc[4];
#pragma unroll
    for (int nt = 0; nt < 4; ++nt) acc[nt] = v4f{0.f, 0.f, 0.f, 0.f};
#pragma unroll
    for (int kt = 0; kt < 8; ++kt) {
      const v8h a = *(const v8h*)(afwd + kt * 32);
#pragma unroll
      for (int nt = 0; nt < 4; ++nt)
        acc[nt] = __builtin_amdgcn_mfma_f32_16x16x32_f16(a, wf[kt][nt], acc[nt], 0, 0, 0);
    }
#pragma unroll
    for (int kt = 8; kt < 16; ++kt) {
      const v8h a = *(const v8h*)(abwd + (kt - 8) * 32);
#pragma unroll
      for (int nt = 0; nt < 4; ++nt)
        acc[nt] = __builtin_amdgcn_mfma_f32_16x16x32_f16(a, wf[kt][nt], acc[nt], 0, 0, 0);
    }
    // C-frag: row(b') = w*16+hp*4+r, col(gate) = nt*256+col -> one 16B store per nt
    float* drow = gxq + (((size_t)tloc * 2 + d) * G4H) * (size_t)BB + w * 16 + hp * 4;
#pragma unroll
    for (int nt = 0; nt < 4; ++nt)
      *(v4f*)(drow + (size_t)(nt * HH + col) * BB) = acc[nt];
  }
}

// -------- persistent gate-split LSTM scan (tagged exchange, 2-phase read) --------
// grid 128; active blocks: (blk&7)<2 -> dir d = blk&7, slice g = blk>>3 (0..15).
// Exchange word = (tag16<<16)|h_fp16 in u32 hexu[d][parity][b][col]. Writer: 4 relaxed
// agent u32 stores, NO vmcnt, NO publish (tag rides with data; 4B word atomicity).
// Reader (plane w):
//   Phase A: 16 lanes poll ONE proxy word per peer WG (row w*16+15, col g'*16+15 —
//            that writer lane's LAST-issued store). 64B/wave/attempt -> no load storm
//            (round-9 lesson: bulk-retry flooded L3 and delayed the polled stores).
//   Phase B: ONE bulk read, 16 x global_load_dwordx4 sc0 (L1-bypass), validate all
//            64 tags; rare straggler -> retry B. B self-validates, so A needs no
//            correctness property.
// Safety: plane-closed double buffer — writer overwrites parity (t+1)&1 at t+1 only
// after reading tag t from ALL plane peers; their tag-t stores are data-dependent on
// completed tag-(t-1) reads of that parity. Max skew 2 + exact-match tags + TAGBASE
// per layer + h_ex memset 0xFF (re-run each replay) kill ABA. Watchdog: shared A+B
// per-wave budget, wave-uniform break, no barriers -> no hang.
// GX==1: gate-init from fp32 gxq, register-prefetched one step ahead, added AFTER
// the recurrent MFMAs. GX==0 (LAYER 1): in-scan gate GEMM fallback.
// Phasing (LAYER 1): [t0,t1) window; c/h carried via cst across launches.
template <int LAYER, int GX>
__global__ __launch_bounds__(256, 1)
void lstm_scan(const float* __restrict__ Whh, const float* __restrict__ Wih0,
               const float* __restrict__ bih, const float* __restrict__ bhh,
               const _Float16* __restrict__ xpad, const float* __restrict__ gxq,
               const _Float16* __restrict__ h1in,
               _Float16* __restrict__ h1out, float* __restrict__ feat,
               unsigned* __restrict__ h_ex,
               const int* __restrict__ lengths, float* __restrict__ cst,
               int t0, int t1) {
  const int blk = blockIdx.x;
  if ((blk & 7) >= 2) return;
  const int d = blk & 7;
  const int g = blk >> 3;
  const int tid = threadIdx.x;
  const int w = tid >> 6;        // wave id = batch tile = sync plane
  const int l = tid & 63;
  const int l15 = l & 15;
  const int hp = l >> 4;
  const int col = g * KC + l15;  // owned h-column
  const unsigned TAGBASE = LAYER * 1024u;

  // persistent W_hh fragments (B-operand layout: lane = W[j=nt*256+col][k=kt*32+hp*8+e])
  v8h wfrag[8][4];
#pragma unroll
  for (int kt = 0; kt < 8; ++kt) {
#pragma unroll
    for (int nt = 0; nt < 4; ++nt) {
      const int j = nt * HH + col;
      const float* src = Whh + ((size_t)d * G4H + j) * HH + kt * 32 + hp * 8;
      HFP8 p;
#pragma unroll
      for (int e = 0; e < 8; ++e) p.h[e] = (_Float16)src[e];
      wfrag[kt][nt] = p.v;
    }
  }
  float bias[4];
#pragma unroll
  for (int nt = 0; nt < 4; ++nt)
    bias[nt] = bih[d * G4H + nt * HH + col] + bhh[d * G4H + nt * HH + col];

  v8h xfrag[4];  // layer 0: W_ih_l0 (K=3 padded to 32)
  if (LAYER == 0) {
#pragma unroll
    for (int nt = 0; nt < 4; ++nt) {
      const int j = nt * HH + col;
      HFP8 p;
#pragma unroll
      for (int e = 0; e < 8; ++e) {
        const int kl = hp * 8 + e;
        p.h[e] = (kl < 3) ? (_Float16)Wih0[((size_t)d * G4H + j) * 3 + kl] : (_Float16)0.f;
      }
      xfrag[nt] = p.v;
    }
  }
  v8h w1frag[16][4];  // layer-1 fallback: W_ih_l1 slice, B-fragments (K=512)
  if (LAYER == 1 && GX == 0) {
#pragma unroll
    for (int kt = 0; kt < 16; ++kt)
#pragma unroll
      for (int nt = 0; nt < 4; ++nt)
        w1frag[kt][nt] =
            *(const v8h*)((const _Float16*)Wih0 +  // reuse Wih0 slot for w1h
                          ((size_t)d * G4H + nt * HH + col) * 512 + kt * 32 + hp * 8);
  }

  int Lr[4];
#pragma unroll
  for (int r = 0; r < 4; ++r) Lr[r] = lengths[w * 16 + hp * 4 + r];
  const int bb = w * 16 + l15;
  const int La = lengths[bb];  // lane's A-row length (fallback path)

  float c_reg[4] = {0.f, 0.f, 0.f, 0.f};
  float h_reg[4] = {0.f, 0.f, 0.f, 0.f};
  if (LAYER == 1 && t0 > 0) {  // phased restore (written by previous launch)
#pragma unroll
    for (int r = 0; r < 4; ++r) {
      const size_t ix = ((size_t)d * BB + (w * 16 + hp * 4 + r)) * HH + col;
      c_reg[r] = cst[ix];
      h_reg[r] = cst[(size_t)2 * BB * HH + ix];
    }
  }

  unsigned* hexu_d = h_ex + (size_t)d * 2 * BB * HH;  // u32 words, parity-double-buffered
  int guard = 0;

  // prefetch gate-init input for first step
  v8h xr;      // layer 0
  v4f gxr[4];  // layer 1 (GX path, fp32)
  if (LAYER == 0) {
    xr = *(const v8h*)(xpad + (((size_t)d * TT + t0) * BB + bb) * 32 + hp * 8);
  } else if (GX) {
    const float* gp = gxq + ((size_t)0 * 2 + d) * G4H * (size_t)BB + w * 16 + hp * 4;
#pragma unroll
    for (int nt = 0; nt < 4; ++nt)
      gxr[nt] = *(const v4f*)(gp + (size_t)(nt * HH + col) * BB);
  }

  for (int t = t0; t < t1; ++t) {
    v4f acc[4];
#pragma unroll
    for (int nt = 0; nt < 4; ++nt) acc[nt] = v4f{bias[nt], bias[nt], bias[nt], bias[nt]};

    if (LAYER == 1 && GX == 0) {
      // fallback in-scan gate GEMM (memory-fed; BEFORE the poll to overlap)
      const int p = (d == 0) ? t : ((t < La) ? (La - 1 - t) : t);
      const int s = (p < La) ? (La - 1 - p) : p;
      const _Float16* afwd = h1in + (((size_t)p * 2 + 0) * BB + bb) * HH + hp * 8;
      const _Float16* abwd = h1in + (((size_t)s * 2 + 1) * BB + bb) * HH + hp * 8;
#pragma unroll
      for (int kt = 0; kt < 8; ++kt) {
        const v8h a = *(const v8h*)(afwd + kt * 32);
#pragma unroll
        for (int nt = 0; nt < 4; ++nt)
          acc[nt] = __builtin_amdgcn_mfma_f32_16x16x32_f16(a, w1frag[kt][nt], acc[nt], 0, 0, 0);
      }
#pragma unroll
      for (int kt = 8; kt < 16; ++kt) {
        const v8h a = *(const v8h*)(abwd + (kt - 8) * 32);
#pragma unroll
        for (int nt = 0; nt < 4; ++nt)
          acc[nt] = __builtin_amdgcn_mfma_f32_16x16x32_f16(a, w1frag[kt][nt], acc[nt], 0, 0, 0);
      }
    }

    if (t > 0) {
      const unsigned* srcu = hexu_d + ((t - 1) & 1) * BB * HH;
      const unsigned expw = TAGBASE + (unsigned)(t - 1);
      int ok = 1;

      // ---- Phase A: cheap proxy poll (64B/wave/attempt) ----
      {
        const int prow = (w * 16 + 15) * HH;
        for (;;) {
          unsigned v = expw << 16;
          if (l < NSL)
            v = __hip_atomic_load(&srcu[prow + l * 16 + 15], __ATOMIC_RELAXED,
                                  __HIP_MEMORY_SCOPE_AGENT);
          if (__all((v >> 16) == expw)) break;
          __builtin_amdgcn_s_sleep(1);
          if (++guard > SPIN_LIM) { ok = 0; break; }
        }
      }
      if (!ok) break;  // wave-uniform; peers also time out. No hang.

      // ---- Phase B: one bulk validated read (16 x dwordx4, L1-bypass) ----
      u32x4 q[16];
      const unsigned* basep = srcu + bb * HH + hp * 8;
      for (;;) {
        asm volatile(
            "global_load_dwordx4 %0, %16, off sc0\n\t"
            "global_load_dwordx4 %1, %16, off offset:16 sc0\n\t"
            "global_load_dwordx4 %2, %16, off offset:128 sc0\n\t"
            "global_load_dwordx4 %3, %16, off offset:144 sc0\n\t"
            "global_load_dwordx4 %4, %16, off offset:256 sc0\n\t"
            "global_load_dwordx4 %5, %16, off offset:272 sc0\n\t"
            "global_load_dwordx4 %6, %16, off offset:384 sc0\n\t"
            "global_load_dwordx4 %7, %16, off offset:400 sc0\n\t"
            "global_load_dwordx4 %8, %16, off offset:512 sc0\n\t"
            "global_load_dwordx4 %9, %16, off offset:528 sc0\n\t"
            "global_load_dwordx4 %10, %16, off offset:640 sc0\n\t"
            "global_load_dwordx4 %11, %16, off offset:656 sc0\n\t"
            "global_load_dwordx4 %12, %16, off offset:768 sc0\n\t"
            "global_load_dwordx4 %13, %16, off offset:784 sc0\n\t"
            "global_load_dwordx4 %14, %16, off offset:896 sc0\n\t"
            "global_load_dwordx4 %15, %16, off offset:912 sc0\n\t"
            "s_waitcnt vmcnt(0)"
            : "=&v"(q[0]), "=&v"(q[1]), "=&v"(q[2]), "=&v"(q[3]),
              "=&v"(q[4]), "=&v"(q[5]), "=&v"(q[6]), "=&v"(q[7]),
              "=&v"(q[8]), "=&v"(q[9]), "=&v"(q[10]), "=&v"(q[11]),
              "=&v"(q[12]), "=&v"(q[13]), "=&v"(q[14]), "=&v"(q[15])
            : "v"(basep)
            : "memory");
        int good = 1;
#pragma unroll
        for (int i = 0; i < 16; ++i)
#pragma unroll
          for (int j = 0; j < 4; ++j) good &= ((q[i][j] >> 16) == expw);
        if (__all(good)) break;
        __builtin_amdgcn_s_sleep(1);
        if (++guard > SPIN_LIM) { ok = 0; break; }
      }
      if (!ok) break;

      // pack fp16 low-halves -> A-fragments, MFMA
#pragma unroll
      for (int kt = 0; kt < 8; ++kt) {
        union { unsigned u[4]; v8h v; } pk;
        pk.u[0] = (q[2 * kt][0] & 0xffffu) | (q[2 * kt][1] << 16);
        pk.u[1] = (q[2 * kt][2] & 0xffffu) | (q[2 * kt][3] << 16);
        pk.u[2] = (q[2 * kt + 1][0] & 0xffffu) | (q[2 * kt + 1][1] << 16);
        pk.u[3] = (q[2 * kt + 1][2] & 0xffffu) | (q[2 * kt + 1][3] << 16);
#pragma unroll
        for (int nt = 0; nt < 4; ++nt)
          acc[nt] = __builtin_amdgcn_mfma_f32_16x16x32_f16(pk.v, wfrag[kt][nt], acc[nt], 0, 0, 0);
      }
    }

    // gate-init contribution AFTER the recurrent MFMAs (prefetch latency hidden)
    if (LAYER == 0) {
#pragma unroll
      for (int nt = 0; nt < 4; ++nt)
        acc[nt] = __builtin_amdgcn_mfma_f32_16x16x32_f16(xr, xfrag[nt], acc[nt], 0, 0, 0);
    } else if (GX) {
#pragma unroll
      for (int nt = 0; nt < 4; ++nt) acc[nt] += gxr[nt];
    }

    unsigned* dstu = hexu_d + (t & 1) * BB * HH;
    const unsigned tagw = (TAGBASE + (unsigned)t) << 16;
#pragma unroll
    for (int r = 0; r < 4; ++r) {
      const int m = w * 16 + hp * 4 + r;
      const float iv = acc[0][r], fv = acc[1][r], gv = acc[2][r], ov = acc[3][r];
      const float cn = fsig(fv) * c_reg[r] + fsig(iv) * ftanh(gv);
      const float hn = fsig(ov) * ftanh(cn);
      const bool valid = t < Lr[r];
      if (valid) { c_reg[r] = cn; h_reg[r] = hn; }
      union { _Float16 f; unsigned short s; } hb;
      hb.f = (_Float16)h_reg[r];
      __hip_atomic_store(&dstu[m * HH + col], tagw | (unsigned)hb.s, __ATOMIC_RELAXED,
                         __HIP_MEMORY_SCOPE_AGENT);
      if (LAYER == 1 && d == 1 && t == 0) {
        feat[m * 512 + HH + col] = h_reg[r];  // bwd out at orig t=L-1 == first bwd step
      }
    }
    // NO vmcnt, NO publish: tagged stores drain autonomously; readers validate.

    // ---- off the critical path ----
    if (LAYER == 0) {  // h1 store, coalesced [t][d][b][256], scan-step order
      _Float16* hr = h1out + (((size_t)t * 2 + d) * BB) * HH + col;
#pragma unroll
      for (int r = 0; r < 4; ++r)
        hr[(size_t)(w * 16 + hp * 4 + r) * HH] =
            (t < Lr[r]) ? (_Float16)h_reg[r] : (_Float16)0.f;
    }
    // next-step gate-init prefetch (flies during the next poll window)
    const int tp = (t + 1 < t1) ? t + 1 : t;
    if (LAYER == 0) {
      xr = *(const v8h*)(xpad + (((size_t)d * TT + tp) * BB + bb) * 32 + hp * 8);
    } else if (GX) {
      const float* gp =
          gxq + (((size_t)(tp - t0) * 2 + d) * G4H) * (size_t)BB + w * 16 + hp * 4;
#pragma unroll
      for (int nt = 0; nt < 4; ++nt)
        gxr[nt] = *(const v4f*)(gp + (size_t)(nt * HH + col) * BB);
    }
  }

  if (LAYER == 1 && t1 < TT) {  // phased save
#pragma unroll
    for (int r = 0; r < 4; ++r) {
      const size_t ix = ((size_t)d * BB + (w * 16 + hp * 4 + r)) * HH + col;
      cst[ix] = c_reg[r];
      cst[(size_t)2 * BB * HH + ix] = h_reg[r];
    }
  }
  if (LAYER == 1 && d == 0 && t1 == TT) {  // fwd final state (frozen at t=L-1)
#pragma unroll
    for (int r = 0; r < 4; ++r) feat[(w * 16 + hp * 4 + r) * 512 + col] = h_reg[r];
  }
}

// ---------------- head ----------------
__global__ void head_fc1(const float* __restrict__ feat, const float* __restrict__ w,
                         const float* __restrict__ b, float* __restrict__ y) {
  const int bb = blockIdx.x, o = threadIdx.x;
  __shared__ float f[512];
  f[o] = feat[bb * 512 + o];
  f[o + 256] = feat[bb * 512 + 256 + o];
  __syncthreads();
  float acc = b[o];
  const float* wr = w + (size_t)o * 512;
  for (int i = 0; i < 512; ++i) acc = fmaf(f[i], wr[i], acc);
  y[bb * 256 + o] = fmaxf(acc, 0.f);
}
__global__ void head_bn(const float* __restrict__ y, const float* __restrict__ gamma,
                        const float* __restrict__ beta, float* __restrict__ ss) {
  const int o = threadIdx.x;
  float s1 = 0.f, s2 = 0.f;
  for (int b = 0; b < 64; ++b) { const float v = y[b * 256 + o]; s1 += v; s2 += v * v; }
  const float mean = s1 * 0.015625f;
  const float var = s2 * 0.015625f - mean * mean;
  const float sc = gamma[o] * __builtin_amdgcn_rsqf(var + 1e-5f);
  ss[o] = sc;
  ss[256 + o] = beta[o] - mean * sc;
}
__global__ void head_out(const float* __restrict__ y, const float* __restrict__ ss,
                         const float* __restrict__ w, const float* __restrict__ b,
                         float* __restrict__ out) {
  const int bb = blockIdx.x, q = threadIdx.x;
  __shared__ float z[256];
  z[q] = y[bb * 256 + q] * ss[q] + ss[256 + q];
  __syncthreads();
  if (q < 196) {
    float acc = b[q];
    const float* wr = w + (size_t)q * 256;
    for (int o = 0; o < 256; ++o) acc = fmaf(z[o], wr[o], acc);
    out[bb * 196 + q] = acc;
  }
}

extern "C" void kernel_launch(void* const* d_in, const int* in_sizes, int n_in,
                              void* d_out, int out_size, void* d_ws, size_t ws_size,
                              hipStream_t stream) {
  const float* x       = (const float*)d_in[0];
  const int* lengths   = (const int*)d_in[1];
  const float* W_ih_l0 = (const float*)d_in[2];
  const float* W_hh_l0 = (const float*)d_in[3];
  const float* b_ih_l0 = (const float*)d_in[4];
  const float* b_hh_l0 = (const float*)d_in[5];
  const float* W_ih_l1 = (const float*)d_in[6];
  const float* W_hh_l1 = (const float*)d_in[7];
  const float* b_ih_l1 = (const float*)d_in[8];
  const float* b_hh_l1 = (const float*)d_in[9];
  const float* fc1_w   = (const float*)d_in[10];
  const float* fc1_b   = (const float*)d_in[11];
  const float* bn_g    = (const float*)d_in[12];
  const float* bn_b    = (const float*)d_in[13];
  const float* fco_w   = (const float*)d_in[14];
  const float* fco_b   = (const float*)d_in[15];
  float* out = (float*)d_out;

  char* ws = (char*)d_ws;
  size_t off = 0;
  auto alloc = [&](size_t sz) { char* p = ws + off; off += (sz + 255) & ~(size_t)255; return p; };
  float* feat      = (float*)alloc(BB * 512 * 4);
  float* ybuf      = (float*)alloc(BB * 256 * 4);
  float* ss        = (float*)alloc(2 * 256 * 4);
  unsigned* h_ex   = (unsigned*)alloc((size_t)2 * 2 * BB * HH * 4);   // tagged u32 words
  float* cst       = (float*)alloc(2 * 2 * BB * HH * 4);              // c|h phase carry
  _Float16* w1h    = (_Float16*)alloc((size_t)2 * 1024 * 512 * 2);
  _Float16* h1     = (_Float16*)alloc((size_t)TT * 2 * BB * HH * 2);  // [t][d][b][256]
  size_t xpad_off  = off;
  _Float16* xpad   = (_Float16*)alloc((size_t)2 * TT * BB * 32 * 2);
  // base total ~78 MB

  if (off > ws_size) {  // distinct signal: NaN output instead of zeros
    hipMemsetAsync(d_out, 0xFF, (size_t)out_size * 4, stream);
    return;
  }

  // gx buffer (fp32) overlays xpad (dead after scan0) and all tail space.
  // CH = t-steps per phase that fit; < TCHUNK -> in-scan fallback.
  const size_t perT = (size_t)2 * G4H * BB * 4;  // 512 KB per t-step (both dirs)
  size_t gx_avail = ws_size - xpad_off;
  int CH = (int)(gx_avail / perT);
  if (CH > TT) CH = TT;
  CH &= ~(TCHUNK - 1);
  float* gxbuf = (float*)(ws + xpad_off);

  // h_ex -> 0xFF: tag 0xFFFF never matches any expected tag (<= 2047)
  hipMemsetAsync(h_ex, 0xFF, (size_t)2 * 2 * BB * HH * 4, stream);

  prep_w1<<<(2 * 1024 * 512 + 255) / 256, 256, 0, stream>>>(W_ih_l1, w1h);
  prep_x<<<(2 * TT * BB * 32 + 255) / 256, 256, 0, stream>>>(x, lengths, xpad);

  lstm_scan<0, 0><<<128, 256, 0, stream>>>(W_hh_l0, W_ih_l0, b_ih_l0, b_hh_l0, xpad,
                                           nullptr, nullptr, h1, nullptr, h_ex,
                                           lengths, nullptr, 0, TT);
  if (CH >= TCHUNK) {
    const int np = (TT + CH - 1) / CH;
    for (int k = 0; k < np; ++k) {
      const int t0 = k * CH;
      const int t1 = (t0 + CH < TT) ? (t0 + CH) : TT;
      gx1_gemm<<<2 * 16 * ((t1 - t0) / TCHUNK), 256, 0, stream>>>(h1, w1h, lengths,
                                                                  gxbuf, t0);
      lstm_scan<1, 1><<<128, 256, 0, stream>>>(W_hh_l1, nullptr, b_ih_l1, b_hh_l1,
                                               nullptr, gxbuf, h1, nullptr, feat, h_ex,
                                               lengths, cst, t0, t1);
    }
  } else {  // fallback: in-scan gate GEMM (w1h passed through the Wih0 slot)
    lstm_scan<1, 0><<<128, 256, 0, stream>>>(W_hh_l1, (const float*)w1h, b_ih_l1,
                                             b_hh_l1, nullptr, nullptr, h1, nullptr,
                                             feat, h_ex, lengths, cst, 0, TT);
  }

  head_fc1<<<64, 256, 0, stream>>>(feat, fc1_w, fc1_b, ybuf);
  head_bn<<<1, 256, 0, stream>>>(ybuf, bn_g, bn_b, ss);
  head_out<<<64, 256, 0, stream>>>(ybuf, ss, fco_w, fco_b, out);
}

// Round 11
// 7758.947 us; speedup vs baseline: 4.2396x; 1.2103x over previous
//
#include <hip/hip_runtime.h>
#include <stdint.h>

#define HH 256
#define BB 64
#define TT 1024
#define G4H 1024
#define NSL 16              // workgroups per direction (gate-split)
#define KC 16               // h-columns owned per WG
#define SPIN_LIM (1 << 17)  // per-wave retry/spin budget -> fast wrong answer, no hang
#define TCHUNK 64           // t-steps per gx1_gemm block

typedef _Float16 v8h __attribute__((ext_vector_type(8)));
typedef float v4f __attribute__((ext_vector_type(4)));
typedef unsigned u32x4 __attribute__((ext_vector_type(4)));

union HFP8 { _Float16 h[8]; v8h v; };
union ULL2F { unsigned long long u[2]; v8h v; };

__device__ __forceinline__ float fsig(float x) {
  float e = __builtin_amdgcn_exp2f(x * -1.44269504f);
  return __builtin_amdgcn_rcpf(1.f + e);
}
__device__ __forceinline__ float ftanh(float x) {
  float e = __builtin_amdgcn_exp2f(x * 2.88539008f);
  return 1.f - 2.f * __builtin_amdgcn_rcpf(e + 1.f);
}

// ---------------- prep kernels ----------------
__global__ void prep_w1(const float* __restrict__ w, _Float16* __restrict__ wh) {
  int i = blockIdx.x * 256 + threadIdx.x;
  if (i < 2 * 1024 * 512) wh[i] = (_Float16)w[i];
}

// xpad[d][t][b][32] fp16 : x (or reversed x) padded to K=32
__global__ void prep_x(const float* __restrict__ x, const int* __restrict__ lengths,
                       _Float16* __restrict__ xpad) {
  int i = blockIdx.x * 256 + threadIdx.x;
  if (i >= 2 * TT * BB * 32) return;
  int k = i & 31, bb = (i >> 5) & 63, t = (i >> 11) & 1023, d = (i >> 21) & 1;
  float v = 0.f;
  if (k < 3) {
    int L = lengths[bb];
    int rt = (d == 0) ? t : ((t < L) ? (L - 1 - t) : t);
    v = x[((size_t)bb * TT + rt) * 3 + k];
  }
  xpad[i] = (_Float16)v;
}

// ---------------- layer-1 gate-init GEMM (hoisted, PHASED, fp32 out) ----------------
// h1 layout [t][d][b][256] in SCAN-STEP order (bwd not re-reversed). Input row of
// layer-1 dir d at scan step t = [h1[p][0][b], h1[s][1][b]] with
// p = (d==0)? t : ((t<L)? L-1-t : t),  s = (p<L)? L-1-p : p   (for d==1, s==t).
// Output gxq[tloc][d][gate][b] fp32 for t in [t0, t0 + 64*gridT).
__global__ __launch_bounds__(256, 1)
void gx1_gemm(const _Float16* __restrict__ h1, const _Float16* __restrict__ w1h,
              const int* __restrict__ lengths, float* __restrict__ gxq, int t0) {
  const int blk = blockIdx.x;
  const int d = blk & 1;
  const int g = (blk >> 1) & 15;
  const int tc = blk >> 5;
  const int tid = threadIdx.x;
  const int w = tid >> 6;
  const int l = tid & 63;
  const int l15 = l & 15;
  const int hp = l >> 4;
  const int col = g * KC + l15;

  // B-fragments: W_ih_l1 rows {nt*256+col}, K=512 (k<256 fwd half, k>=256 bwd half)
  v8h wf[16][4];
#pragma unroll
  for (int kt = 0; kt < 16; ++kt)
#pragma unroll
    for (int nt = 0; nt < 4; ++nt)
      wf[kt][nt] =
          *(const v8h*)(w1h + ((size_t)d * G4H + nt * HH + col) * 512 + kt * 32 + hp * 8);

  const int b = w * 16 + l15;  // this lane's A-row (batch)
  const int L = lengths[b];

  for (int i = 0; i < TCHUNK; ++i) {
    const int t = t0 + tc * TCHUNK + i;
    const int tloc = t - t0;
    const int p = (d == 0) ? t : ((t < L) ? (L - 1 - t) : t);
    const int s = (p < L) ? (L - 1 - p) : p;
    const _Float16* afwd = h1 + (((size_t)p * 2 + 0) * BB + b) * HH + hp * 8;
    const _Float16* abwd = h1 + (((size_t)s * 2 + 1) * BB + b) * HH + hp * 8;
    v4f acc[4];
#pragma unroll
    for (int nt = 0; nt < 4; ++nt) acc[nt] = v4f{0.f, 0.f, 0.f, 0.f};
#pragma unroll
    for (int kt = 0; kt < 8; ++kt) {
      const v8h a = *(const v8h*)(afwd + kt * 32);
#pragma unroll
      for (int nt = 0; nt < 4; ++nt)
        acc[nt] = __builtin_amdgcn_mfma_f32_16x16x32_f16(a, wf[kt][nt], acc[nt], 0, 0, 0);
    }
#pragma unroll
    for (int kt = 8; kt < 16; ++kt) {
      const v8h a = *(const v8h*)(abwd + (kt - 8) * 32);
#pragma unroll
      for (int nt = 0; nt < 4; ++nt)
        acc[nt] = __builtin_amdgcn_mfma_f32_16x16x32_f16(a, wf[kt][nt], acc[nt], 0, 0, 0);
    }
    // C-frag: row(b') = w*16+hp*4+r, col(gate) = nt*256+col -> one 16B store per nt
    float* drow = gxq + (((size_t)tloc * 2 + d) * G4H) * (size_t)BB + w * 16 + hp * 4;
#pragma unroll
    for (int nt = 0; nt < 4; ++nt)
      *(v4f*)(drow + (size_t)(nt * HH + col) * BB) = acc[nt];
  }
}

// -------- persistent gate-split LSTM scan (HYBRID protocol, measured-best per layer) --------
// grid 128; active blocks: (blk&7)<2 -> dir d = blk&7, slice g = blk>>3 (0..15).
// LAYER 0 (tagged two-phase, round-10-measured 3.28ms): exchange word =
//   (tag16<<16)|h_fp16 in u32. Writer: 4 relaxed agent u32 stores, no vmcnt/publish.
//   Reader: Phase A polls ONE proxy word per peer WG (64B/wave/attempt); Phase B one
//   bulk 16 x dwordx4 sc0 read, validate all 64 tags, rare retry. Plane-closed
//   double-buffer + exact tags + 0xFF memset kill ABA.
// LAYER 1 (per-wave publish/poll, round-7-measured): u16 h words; per-wave flow =
//   4 agent h-stores -> s_waitcnt vmcnt(0) -> lane0 publishes prog[d][g][w] -> peers
//   poll their plane's 16 words, then 16 x 8B agent loads. (Round-10's tagged scheme
//   REGRESSED scan1 ~1.7ms — mechanism unconfirmed; this round is the attribution test.)
// Watchdog both paths: per-wave budget, wave-uniform break, no barriers -> no hang.
// GX==1: gate-init from fp32 gxq, register-prefetched one step ahead, added AFTER the
// recurrent MFMAs. GX==0 (LAYER 1): in-scan gate GEMM fallback.
// Phasing (LAYER 1): [t0,t1) window; c/h carried via cst across launches.
template <int LAYER, int GX>
__global__ __launch_bounds__(256, 1)
void lstm_scan(const float* __restrict__ Whh, const float* __restrict__ Wih0,
               const float* __restrict__ bih, const float* __restrict__ bhh,
               const _Float16* __restrict__ xpad, const float* __restrict__ gxq,
               const _Float16* __restrict__ h1in,
               _Float16* __restrict__ h1out, float* __restrict__ feat,
               unsigned* __restrict__ h_ex, int* __restrict__ prog,
               const int* __restrict__ lengths, float* __restrict__ cst,
               int t0, int t1) {
  const int blk = blockIdx.x;
  if ((blk & 7) >= 2) return;
  const int d = blk & 7;
  const int g = blk >> 3;
  const int tid = threadIdx.x;
  const int w = tid >> 6;        // wave id = batch tile = sync plane
  const int l = tid & 63;
  const int l15 = l & 15;
  const int hp = l >> 4;
  const int col = g * KC + l15;  // owned h-column

  // persistent W_hh fragments (B-operand layout: lane = W[j=nt*256+col][k=kt*32+hp*8+e])
  v8h wfrag[8][4];
#pragma unroll
  for (int kt = 0; kt < 8; ++kt) {
#pragma unroll
    for (int nt = 0; nt < 4; ++nt) {
      const int j = nt * HH + col;
      const float* src = Whh + ((size_t)d * G4H + j) * HH + kt * 32 + hp * 8;
      HFP8 p;
#pragma unroll
      for (int e = 0; e < 8; ++e) p.h[e] = (_Float16)src[e];
      wfrag[kt][nt] = p.v;
    }
  }
  float bias[4];
#pragma unroll
  for (int nt = 0; nt < 4; ++nt)
    bias[nt] = bih[d * G4H + nt * HH + col] + bhh[d * G4H + nt * HH + col];

  v8h xfrag[4];  // layer 0: W_ih_l0 (K=3 padded to 32)
  if (LAYER == 0) {
#pragma unroll
    for (int nt = 0; nt < 4; ++nt) {
      const int j = nt * HH + col;
      HFP8 p;
#pragma unroll
      for (int e = 0; e < 8; ++e) {
        const int kl = hp * 8 + e;
        p.h[e] = (kl < 3) ? (_Float16)Wih0[((size_t)d * G4H + j) * 3 + kl] : (_Float16)0.f;
      }
      xfrag[nt] = p.v;
    }
  }
  v8h w1frag[16][4];  // layer-1 fallback: W_ih_l1 slice, B-fragments (K=512)
  if (LAYER == 1 && GX == 0) {
#pragma unroll
    for (int kt = 0; kt < 16; ++kt)
#pragma unroll
      for (int nt = 0; nt < 4; ++nt)
        w1frag[kt][nt] =
            *(const v8h*)((const _Float16*)Wih0 +  // reuse Wih0 slot for w1h
                          ((size_t)d * G4H + nt * HH + col) * 512 + kt * 32 + hp * 8);
  }

  int Lr[4];
#pragma unroll
  for (int r = 0; r < 4; ++r) Lr[r] = lengths[w * 16 + hp * 4 + r];
  const int bb = w * 16 + l15;
  const int La = lengths[bb];  // lane's A-row length (fallback path)

  float c_reg[4] = {0.f, 0.f, 0.f, 0.f};
  float h_reg[4] = {0.f, 0.f, 0.f, 0.f};
  if (LAYER == 1 && t0 > 0) {  // phased restore (written by previous launch)
#pragma unroll
    for (int r = 0; r < 4; ++r) {
      const size_t ix = ((size_t)d * BB + (w * 16 + hp * 4 + r)) * HH + col;
      c_reg[r] = cst[ix];
      h_reg[r] = cst[(size_t)2 * BB * HH + ix];
    }
  }

  unsigned* hexu_d = h_ex + (size_t)d * 2 * BB * HH;          // u32 view (layer 0)
  short* hexs_d = (short*)h_ex + (size_t)d * 2 * BB * HH;     // u16 view (layer 1)
  int* prg = prog + d * NSL * 4 * 16;                         // [g][w] words, 64B padded
  int guard = 0;

  // prefetch gate-init input for first step
  v8h xr;      // layer 0
  v4f gxr[4];  // layer 1 (GX path, fp32)
  if (LAYER == 0) {
    xr = *(const v8h*)(xpad + (((size_t)d * TT + t0) * BB + bb) * 32 + hp * 8);
  } else if (GX) {
    const float* gp = gxq + ((size_t)0 * 2 + d) * G4H * (size_t)BB + w * 16 + hp * 4;
#pragma unroll
    for (int nt = 0; nt < 4; ++nt)
      gxr[nt] = *(const v4f*)(gp + (size_t)(nt * HH + col) * BB);
  }

  for (int t = t0; t < t1; ++t) {
    v4f acc[4];
#pragma unroll
    for (int nt = 0; nt < 4; ++nt) acc[nt] = v4f{bias[nt], bias[nt], bias[nt], bias[nt]};

    if (LAYER == 1 && GX == 0) {
      // fallback in-scan gate GEMM (memory-fed; BEFORE the poll to overlap)
      const int p = (d == 0) ? t : ((t < La) ? (La - 1 - t) : t);
      const int s = (p < La) ? (La - 1 - p) : p;
      const _Float16* afwd = h1in + (((size_t)p * 2 + 0) * BB + bb) * HH + hp * 8;
      const _Float16* abwd = h1in + (((size_t)s * 2 + 1) * BB + bb) * HH + hp * 8;
#pragma unroll
      for (int kt = 0; kt < 8; ++kt) {
        const v8h a = *(const v8h*)(afwd + kt * 32);
#pragma unroll
        for (int nt = 0; nt < 4; ++nt)
          acc[nt] = __builtin_amdgcn_mfma_f32_16x16x32_f16(a, w1frag[kt][nt], acc[nt], 0, 0, 0);
      }
#pragma unroll
      for (int kt = 8; kt < 16; ++kt) {
        const v8h a = *(const v8h*)(abwd + (kt - 8) * 32);
#pragma unroll
        for (int nt = 0; nt < 4; ++nt)
          acc[nt] = __builtin_amdgcn_mfma_f32_16x16x32_f16(a, w1frag[kt][nt], acc[nt], 0, 0, 0);
      }
    }

    if (t > 0) {
      if (LAYER == 0) {
        // ======== tagged two-phase exchange (round-10-measured best for scan0) ========
        const unsigned* srcu = hexu_d + ((t - 1) & 1) * BB * HH;
        const unsigned expw = (unsigned)(t - 1);
        int ok = 1;

        // Phase A: cheap proxy poll (64B/wave/attempt)
        {
          const int prow = (w * 16 + 15) * HH;
          for (;;) {
            unsigned v = expw << 16;
            if (l < NSL)
              v = __hip_atomic_load(&srcu[prow + l * 16 + 15], __ATOMIC_RELAXED,
                                    __HIP_MEMORY_SCOPE_AGENT);
            if (__all((v >> 16) == expw)) break;
            __builtin_amdgcn_s_sleep(1);
            if (++guard > SPIN_LIM) { ok = 0; break; }
          }
        }
        if (!ok) break;

        // Phase B: one bulk validated read (16 x dwordx4, L1-bypass)
        u32x4 q[16];
        const unsigned* basep = srcu + bb * HH + hp * 8;
        for (;;) {
          asm volatile(
              "global_load_dwordx4 %0, %16, off sc0\n\t"
              "global_load_dwordx4 %1, %16, off offset:16 sc0\n\t"
              "global_load_dwordx4 %2, %16, off offset:128 sc0\n\t"
              "global_load_dwordx4 %3, %16, off offset:144 sc0\n\t"
              "global_load_dwordx4 %4, %16, off offset:256 sc0\n\t"
              "global_load_dwordx4 %5, %16, off offset:272 sc0\n\t"
              "global_load_dwordx4 %6, %16, off offset:384 sc0\n\t"
              "global_load_dwordx4 %7, %16, off offset:400 sc0\n\t"
              "global_load_dwordx4 %8, %16, off offset:512 sc0\n\t"
              "global_load_dwordx4 %9, %16, off offset:528 sc0\n\t"
              "global_load_dwordx4 %10, %16, off offset:640 sc0\n\t"
              "global_load_dwordx4 %11, %16, off offset:656 sc0\n\t"
              "global_load_dwordx4 %12, %16, off offset:768 sc0\n\t"
              "global_load_dwordx4 %13, %16, off offset:784 sc0\n\t"
              "global_load_dwordx4 %14, %16, off offset:896 sc0\n\t"
              "global_load_dwordx4 %15, %16, off offset:912 sc0\n\t"
              "s_waitcnt vmcnt(0)"
              : "=&v"(q[0]), "=&v"(q[1]), "=&v"(q[2]), "=&v"(q[3]),
                "=&v"(q[4]), "=&v"(q[5]), "=&v"(q[6]), "=&v"(q[7]),
                "=&v"(q[8]), "=&v"(q[9]), "=&v"(q[10]), "=&v"(q[11]),
                "=&v"(q[12]), "=&v"(q[13]), "=&v"(q[14]), "=&v"(q[15])
              : "v"(basep)
              : "memory");
          int good = 1;
#pragma unroll
          for (int i = 0; i < 16; ++i)
#pragma unroll
            for (int j = 0; j < 4; ++j) good &= ((q[i][j] >> 16) == expw);
          if (__all(good)) break;
          __builtin_amdgcn_s_sleep(1);
          if (++guard > SPIN_LIM) { ok = 0; break; }
        }
        if (!ok) break;

        // pack fp16 low-halves -> A-fragments, MFMA
#pragma unroll
        for (int kt = 0; kt < 8; ++kt) {
          union { unsigned u[4]; v8h v; } pk;
          pk.u[0] = (q[2 * kt][0] & 0xffffu) | (q[2 * kt][1] << 16);
          pk.u[1] = (q[2 * kt][2] & 0xffffu) | (q[2 * kt][3] << 16);
          pk.u[2] = (q[2 * kt + 1][0] & 0xffffu) | (q[2 * kt + 1][1] << 16);
          pk.u[3] = (q[2 * kt + 1][2] & 0xffffu) | (q[2 * kt + 1][3] << 16);
#pragma unroll
          for (int nt = 0; nt < 4; ++nt)
            acc[nt] = __builtin_amdgcn_mfma_f32_16x16x32_f16(pk.v, wfrag[kt][nt], acc[nt], 0, 0, 0);
        }
      } else {
        // ======== per-wave publish/poll exchange (round-7-measured best for scan1) ========
        int ok = 1;
        for (;;) {
          int v = (l < NSL)
                      ? __hip_atomic_load(&prg[(l * 4 + w) * 16], __ATOMIC_RELAXED,
                                          __HIP_MEMORY_SCOPE_AGENT)
                      : (t - 1);
          if (__all(v >= t - 1)) break;
          __builtin_amdgcn_s_sleep(1);
          if (++guard > SPIN_LIM) { ok = 0; break; }
        }
        if (!ok) break;  // wave-uniform; peers also time out. No hang.

        const unsigned long long* src =
            (const unsigned long long*)(hexs_d + ((t - 1) & 1) * BB * HH);
        const int base = (w * 16 + l15) * 64 + hp * 2;  // ull index into 256-col row
        unsigned long long fr[16];
#pragma unroll
        for (int kt = 0; kt < 8; ++kt) {
          fr[2 * kt] = __hip_atomic_load(src + base + kt * 8, __ATOMIC_RELAXED,
                                         __HIP_MEMORY_SCOPE_AGENT);
          fr[2 * kt + 1] = __hip_atomic_load(src + base + kt * 8 + 1, __ATOMIC_RELAXED,
                                             __HIP_MEMORY_SCOPE_AGENT);
        }
#pragma unroll
        for (int kt = 0; kt < 8; ++kt) {
          ULL2F u;
          u.u[0] = fr[2 * kt];
          u.u[1] = fr[2 * kt + 1];
#pragma unroll
          for (int nt = 0; nt < 4; ++nt)
            acc[nt] = __builtin_amdgcn_mfma_f32_16x16x32_f16(u.v, wfrag[kt][nt], acc[nt], 0, 0, 0);
        }
      }
    }

    // gate-init contribution AFTER the recurrent MFMAs (prefetch latency hidden)
    if (LAYER == 0) {
#pragma unroll
      for (int nt = 0; nt < 4; ++nt)
        acc[nt] = __builtin_amdgcn_mfma_f32_16x16x32_f16(xr, xfrag[nt], acc[nt], 0, 0, 0);
    } else if (GX) {
#pragma unroll
      for (int nt = 0; nt < 4; ++nt) acc[nt] += gxr[nt];
    }

    // gates + h store (protocol-specific word format)
    if (LAYER == 0) {
      unsigned* dstu = hexu_d + (t & 1) * BB * HH;
      const unsigned tagw = ((unsigned)t) << 16;
#pragma unroll
      for (int r = 0; r < 4; ++r) {
        const int m = w * 16 + hp * 4 + r;
        const float iv = acc[0][r], fv = acc[1][r], gv = acc[2][r], ov = acc[3][r];
        const float cn = fsig(fv) * c_reg[r] + fsig(iv) * ftanh(gv);
        const float hn = fsig(ov) * ftanh(cn);
        const bool valid = t < Lr[r];
        if (valid) { c_reg[r] = cn; h_reg[r] = hn; }
        union { _Float16 f; unsigned short s; } hb;
        hb.f = (_Float16)h_reg[r];
        __hip_atomic_store(&dstu[m * HH + col], tagw | (unsigned)hb.s, __ATOMIC_RELAXED,
                           __HIP_MEMORY_SCOPE_AGENT);
      }
      // no vmcnt, no publish (tag rides with data)
    } else {
      short* dst = hexs_d + (t & 1) * BB * HH;
#pragma unroll
      for (int r = 0; r < 4; ++r) {
        const int m = w * 16 + hp * 4 + r;
        const float iv = acc[0][r], fv = acc[1][r], gv = acc[2][r], ov = acc[3][r];
        const float cn = fsig(fv) * c_reg[r] + fsig(iv) * ftanh(gv);
        const float hn = fsig(ov) * ftanh(cn);
        const bool valid = t < Lr[r];
        if (valid) { c_reg[r] = cn; h_reg[r] = hn; }
        union { _Float16 f; short s; } hb;
        hb.f = (_Float16)h_reg[r];
        __hip_atomic_store(&dst[m * HH + col], hb.s, __ATOMIC_RELAXED,
                           __HIP_MEMORY_SCOPE_AGENT);
        if (d == 1 && t == 0) {
          feat[m * 512 + HH + col] = h_reg[r];  // bwd out at orig t=L-1 == first bwd step
        }
      }
      // per-wave: my 4 h-stores at the coherence point -> publish my plane word
      asm volatile("s_waitcnt vmcnt(0)" ::: "memory");
      if (l == 0)
        __hip_atomic_store(&prg[(g * 4 + w) * 16], t, __ATOMIC_RELAXED,
                           __HIP_MEMORY_SCOPE_AGENT);
    }

    // ---- off the critical path ----
    if (LAYER == 0) {  // h1 store, coalesced [t][d][b][256], scan-step order
      _Float16* hr = h1out + (((size_t)t * 2 + d) * BB) * HH + col;
#pragma unroll
      for (int r = 0; r < 4; ++r)
        hr[(size_t)(w * 16 + hp * 4 + r) * HH] =
            (t < Lr[r]) ? (_Float16)h_reg[r] : (_Float16)0.f;
    }
    // next-step gate-init prefetch (flies during the next poll window)
    const int tp = (t + 1 < t1) ? t + 1 : t;
    if (LAYER == 0) {
      xr = *(const v8h*)(xpad + (((size_t)d * TT + tp) * BB + bb) * 32 + hp * 8);
    } else if (GX) {
      const float* gp =
          gxq + (((size_t)(tp - t0) * 2 + d) * G4H) * (size_t)BB + w * 16 + hp * 4;
#pragma unroll
      for (int nt = 0; nt < 4; ++nt)
        gxr[nt] = *(const v4f*)(gp + (size_t)(nt * HH + col) * BB);
    }
  }

  if (LAYER == 1 && t1 < TT) {  // phased save
#pragma unroll
    for (int r = 0; r < 4; ++r) {
      const size_t ix = ((size_t)d * BB + (w * 16 + hp * 4 + r)) * HH + col;
      cst[ix] = c_reg[r];
      cst[(size_t)2 * BB * HH + ix] = h_reg[r];
    }
  }
  if (LAYER == 1 && d == 0 && t1 == TT) {  // fwd final state (frozen at t=L-1)
#pragma unroll
    for (int r = 0; r < 4; ++r) feat[(w * 16 + hp * 4 + r) * 512 + col] = h_reg[r];
  }
}

// ---------------- head ----------------
__global__ void head_fc1(const float* __restrict__ feat, const float* __restrict__ w,
                         const float* __restrict__ b, float* __restrict__ y) {
  const int bb = blockIdx.x, o = threadIdx.x;
  __shared__ float f[512];
  f[o] = feat[bb * 512 + o];
  f[o + 256] = feat[bb * 512 + 256 + o];
  __syncthreads();
  float acc = b[o];
  const float* wr = w + (size_t)o * 512;
  for (int i = 0; i < 512; ++i) acc = fmaf(f[i], wr[i], acc);
  y[bb * 256 + o] = fmaxf(acc, 0.f);
}
__global__ void head_bn(const float* __restrict__ y, const float* __restrict__ gamma,
                        const float* __restrict__ beta, float* __restrict__ ss) {
  const int o = threadIdx.x;
  float s1 = 0.f, s2 = 0.f;
  for (int b = 0; b < 64; ++b) { const float v = y[b * 256 + o]; s1 += v; s2 += v * v; }
  const float mean = s1 * 0.015625f;
  const float var = s2 * 0.015625f - mean * mean;
  const float sc = gamma[o] * __builtin_amdgcn_rsqf(var + 1e-5f);
  ss[o] = sc;
  ss[256 + o] = beta[o] - mean * sc;
}
__global__ void head_out(const float* __restrict__ y, const float* __restrict__ ss,
                         const float* __restrict__ w, const float* __restrict__ b,
                         float* __restrict__ out) {
  const int bb = blockIdx.x, q = threadIdx.x;
  __shared__ float z[256];
  z[q] = y[bb * 256 + q] * ss[q] + ss[256 + q];
  __syncthreads();
  if (q < 196) {
    float acc = b[q];
    const float* wr = w + (size_t)q * 256;
    for (int o = 0; o < 256; ++o) acc = fmaf(z[o], wr[o], acc);
    out[bb * 196 + q] = acc;
  }
}

extern "C" void kernel_launch(void* const* d_in, const int* in_sizes, int n_in,
                              void* d_out, int out_size, void* d_ws, size_t ws_size,
                              hipStream_t stream) {
  const float* x       = (const float*)d_in[0];
  const int* lengths   = (const int*)d_in[1];
  const float* W_ih_l0 = (const float*)d_in[2];
  const float* W_hh_l0 = (const float*)d_in[3];
  const float* b_ih_l0 = (const float*)d_in[4];
  const float* b_hh_l0 = (const float*)d_in[5];
  const float* W_ih_l1 = (const float*)d_in[6];
  const float* W_hh_l1 = (const float*)d_in[7];
  const float* b_ih_l1 = (const float*)d_in[8];
  const float* b_hh_l1 = (const float*)d_in[9];
  const float* fc1_w   = (const float*)d_in[10];
  const float* fc1_b   = (const float*)d_in[11];
  const float* bn_g    = (const float*)d_in[12];
  const float* bn_b    = (const float*)d_in[13];
  const float* fco_w   = (const float*)d_in[14];
  const float* fco_b   = (const float*)d_in[15];
  float* out = (float*)d_out;

  char* ws = (char*)d_ws;
  size_t off = 0;
  auto alloc = [&](size_t sz) { char* p = ws + off; off += (sz + 255) & ~(size_t)255; return p; };
  float* feat      = (float*)alloc(BB * 512 * 4);
  float* ybuf      = (float*)alloc(BB * 256 * 4);
  float* ss        = (float*)alloc(2 * 256 * 4);
  unsigned* h_ex   = (unsigned*)alloc((size_t)2 * 2 * BB * HH * 4);   // u32 (L0) / u16 (L1) views
  int* prog        = (int*)alloc(2 * NSL * 4 * 16 * 4);               // L1 per-(WG,wave) words
  float* cst       = (float*)alloc(2 * 2 * BB * HH * 4);              // c|h phase carry
  _Float16* w1h    = (_Float16*)alloc((size_t)2 * 1024 * 512 * 2);
  _Float16* h1     = (_Float16*)alloc((size_t)TT * 2 * BB * HH * 2);  // [t][d][b][256]
  size_t xpad_off  = off;
  _Float16* xpad   = (_Float16*)alloc((size_t)2 * TT * BB * 32 * 2);
  // base total ~78 MB

  if (off > ws_size) {  // distinct signal: NaN output instead of zeros
    hipMemsetAsync(d_out, 0xFF, (size_t)out_size * 4, stream);
    return;
  }

  // gx buffer (fp32) overlays xpad (dead after scan0) and all tail space.
  // CH = t-steps per phase that fit; < TCHUNK -> in-scan fallback.
  const size_t perT = (size_t)2 * G4H * BB * 4;  // 512 KB per t-step (both dirs)
  size_t gx_avail = ws_size - xpad_off;
  int CH = (int)(gx_avail / perT);
  if (CH > TT) CH = TT;
  CH &= ~(TCHUNK - 1);
  float* gxbuf = (float*)(ws + xpad_off);

  // h_ex -> 0xFF (L0: tag 0xFFFF never expected) | prog -> -1 (L1): contiguous memset
  hipMemsetAsync(h_ex, 0xFF, (size_t)2 * 2 * BB * HH * 4 + 2 * NSL * 4 * 16 * 4, stream);

  prep_w1<<<(2 * 1024 * 512 + 255) / 256, 256, 0, stream>>>(W_ih_l1, w1h);
  prep_x<<<(2 * TT * BB * 32 + 255) / 256, 256, 0, stream>>>(x, lengths, xpad);

  lstm_scan<0, 0><<<128, 256, 0, stream>>>(W_hh_l0, W_ih_l0, b_ih_l0, b_hh_l0, xpad,
                                           nullptr, nullptr, h1, nullptr, h_ex, prog,
                                           lengths, nullptr, 0, TT);
  if (CH >= TCHUNK) {
    const int np = (TT + CH - 1) / CH;
    for (int k = 0; k < np; ++k) {
      const int t0 = k * CH;
      const int t1 = (t0 + CH < TT) ? (t0 + CH) : TT;
      gx1_gemm<<<2 * 16 * ((t1 - t0) / TCHUNK), 256, 0, stream>>>(h1, w1h, lengths,
                                                                  gxbuf, t0);
      lstm_scan<1, 1><<<128, 256, 0, stream>>>(W_hh_l1, nullptr, b_ih_l1, b_hh_l1,
                                               nullptr, gxbuf, h1, nullptr, feat, h_ex,
                                               prog, lengths, cst, t0, t1);
    }
  } else {  // fallback: in-scan gate GEMM (w1h passed through the Wih0 slot)
    lstm_scan<1, 0><<<128, 256, 0, stream>>>(W_hh_l1, (const float*)w1h, b_ih_l1,
                                             b_hh_l1, nullptr, nullptr, h1, nullptr,
                                             feat, h_ex, prog, lengths, cst, 0, TT);
  }

  head_fc1<<<64, 256, 0, stream>>>(feat, fc1_w, fc1_b, ybuf);
  head_bn<<<1, 256, 0, stream>>>(ybuf, bn_g, bn_b, ss);
  head_out<<<64, 256, 0, stream>>>(ybuf, ss, fco_w, fco_b, out);
}